// Round 1
// baseline (494.655 us; speedup 1.0000x reference)
//
#include <hip/hip_runtime.h>

// Problem constants (from setup_inputs): x [4,64,256,256] f32, flow [4,2,256,256] f32
// out [4, 5*64, 256, 256] f32
#define BB 4
#define CC 64
#define HH 256
#define WW 256
#define HWHW (HH * WW)

// Kernel A: transpose x [B,C,H*W] -> xt [B,H*W,C] (channels-last) so that
// bilinear gather taps are coalesced (64 contiguous channel floats per tap).
__global__ __launch_bounds__(256) void transpose_xk(const float* __restrict__ x,
                                                    float* __restrict__ xt) {
    __shared__ float tile[64][65];  // +1 pad: conflict-free both phases
    const int b = blockIdx.y;
    const int hw0 = blockIdx.x << 6;      // 64 pixels per block
    const int t = threadIdx.x;
    const int wv = t >> 6, lane = t & 63;
    const float* xb = x + (size_t)b * CC * HWHW;
#pragma unroll
    for (int k = 0; k < 16; ++k) {
        const int c = (k << 2) + wv;
        tile[c][lane] = xb[(size_t)c * HWHW + hw0 + lane];  // coalesced read
    }
    __syncthreads();
    float* xtb = xt + ((size_t)b * HWHW << 6);
#pragma unroll
    for (int k = 0; k < 16; ++k) {
        const int hw = (k << 2) + wv;
        xtb[((size_t)(hw0 + hw) << 6) + lane] = tile[lane][hw];  // coalesced write
    }
}

// Kernel B: fused 5-variant OBMC warp.
// Block = 256 threads = 4 waves, handles one (b, y, 64-px x-tile).
// Compute phase lane mapping: sp = lane>>4 (pixel within group of 4),
//   c4 = (lane&15)*4 (4 channels per lane, float4 gathers).
// Store phase goes through LDS sm[c][px] (pad 65) for coalesced output.
__global__ __launch_bounds__(256) void obmc_kernel(const float* __restrict__ xt,
                                                   const float* __restrict__ flow,
                                                   float* __restrict__ out) {
    __shared__ float sm[64][65];  // [c][px], +1 pad -> 2-way max (free)
    const int bid = blockIdx.x;
    const int tx0 = (bid & 3) << 6;       // x-tile base (W=256 -> 4 tiles)
    const int y = (bid >> 2) & 255;
    const int b = bid >> 10;
    const int t = threadIdx.x;
    const int wv = t >> 6;
    const int lane = t & 63;
    const int sp = lane >> 4;             // 0..3 : pixel within 4-px group
    const int c4 = (lane & 15) << 2;      // channel base (float4 per lane)

    const float* xtb = xt + ((size_t)b * HWHW << 6);
    const float* fb = flow + (size_t)b * 2 * HWHW;
    float* ob = out + (size_t)b * 5 * CC * HWHW + (size_t)y * WW + tx0;

    // Integer shifts of the flow field implied by _shift(flow, bias):
    // g=0: none; g=1: (y+1,x); g=2: (y,x+1); g=3: (y-1,x); g=4: (y,x-1)
    const int oys[5] = {0, 1, 0, -1, 0};
    const int oxs[5] = {0, 0, 1, 0, -1};

    for (int g = 0; g < 5; ++g) {
        float4 acc[4];
#pragma unroll
        for (int i = 0; i < 4; ++i) {
            const int px = (wv << 4) + (i << 2) + sp;  // pixel in tile
            const int xx = tx0 + px;
            const int sy = y + oys[g];
            const int sx = xx + oxs[g];
            float fx = 0.f, fy = 0.f;
            if (sy >= 0 && sy < HH && sx >= 0 && sx < WW) {
                const int fo = sy * WW + sx;
                fx = fb[fo];           // dx
                fy = fb[HWHW + fo];    // dy
            }
            // zero shifted flow (OOB) => identity sample, handled naturally
            const float gx = (float)xx + fx;
            const float gy = (float)y + fy;
            const float x0f = floorf(gx);
            const float y0f = floorf(gy);
            const float fwx = gx - x0f;
            const float fwy = gy - y0f;
            const int ix0 = (int)x0f;
            const int iy0 = (int)y0f;
            const float w00 = (1.f - fwx) * (1.f - fwy);
            const float w01 = fwx * (1.f - fwy);
            const float w10 = (1.f - fwx) * fwy;
            const float w11 = fwx * fwy;

            float4 a = make_float4(0.f, 0.f, 0.f, 0.f);
            auto tap = [&](int yy, int xv, float w) {
                if (yy >= 0 && yy < HH && xv >= 0 && xv < WW) {
                    const float4 v =
                        *(const float4*)(xtb + (((size_t)(yy * WW + xv) << 6) + c4));
                    a.x = fmaf(w, v.x, a.x);
                    a.y = fmaf(w, v.y, a.y);
                    a.z = fmaf(w, v.z, a.z);
                    a.w = fmaf(w, v.w, a.w);
                }
            };
            tap(iy0,     ix0,     w00);
            tap(iy0,     ix0 + 1, w01);
            tap(iy0 + 1, ix0,     w10);
            tap(iy0 + 1, ix0 + 1, w11);
            acc[i] = a;
        }
        // Phase 1: registers -> LDS (scalar writes, 2-way bank alias = free)
#pragma unroll
        for (int i = 0; i < 4; ++i) {
            const int px = (wv << 4) + (i << 2) + sp;
            sm[c4 + 0][px] = acc[i].x;
            sm[c4 + 1][px] = acc[i].y;
            sm[c4 + 2][px] = acc[i].z;
            sm[c4 + 3][px] = acc[i].w;
        }
        __syncthreads();
        // Phase 2: LDS -> out, lanes along px -> 256B coalesced stores
#pragma unroll
        for (int k = 0; k < 16; ++k) {
            const int c = (wv << 4) + k;
            ob[(size_t)(g * CC + c) * HWHW + lane] = sm[c][lane];
        }
        __syncthreads();  // protect sm before next variant
    }
}

extern "C" void kernel_launch(void* const* d_in, const int* in_sizes, int n_in,
                              void* d_out, int out_size, void* d_ws, size_t ws_size,
                              hipStream_t stream) {
    const float* x = (const float*)d_in[0];      // [4,64,256,256]
    const float* flow = (const float*)d_in[1];   // [4,2,256,256]
    float* out = (float*)d_out;                  // [4,320,256,256]
    float* xt = (float*)d_ws;                    // needs 64 MiB scratch

    transpose_xk<<<dim3(HWHW / 64, BB), 256, 0, stream>>>(x, xt);
    obmc_kernel<<<BB * HH * (WW / 64), 256, 0, stream>>>(xt, flow, out);
}

// Round 2
// 428.387 us; speedup vs baseline: 1.1547x; 1.1547x over previous
//
#include <hip/hip_runtime.h>

// x [4,64,256,256] f32, flow [4,2,256,256] f32 -> out [4,320,256,256] f32
#define BB 4
#define CC 64
#define HH 256
#define WW 256
#define HWHW (HH * WW)

// Kernel A: transpose x [B,C,HW] -> xt [B,HW,C] so gather taps are coalesced.
__global__ __launch_bounds__(256) void transpose_xk(const float* __restrict__ x,
                                                    float* __restrict__ xt) {
    __shared__ float tile[64][65];
    const int b = blockIdx.y;
    const int hw0 = blockIdx.x << 6;
    const int t = threadIdx.x;
    const int wv = t >> 6, lane = t & 63;
    const float* xb = x + (size_t)b * CC * HWHW;
#pragma unroll
    for (int k = 0; k < 16; ++k) {
        const int c = (k << 2) + wv;
        tile[c][lane] = xb[(size_t)c * HWHW + hw0 + lane];
    }
    __syncthreads();
    float* xtb = xt + ((size_t)b * HWHW << 6);
#pragma unroll
    for (int k = 0; k < 16; ++k) {
        const int hw = (k << 2) + wv;
        xtb[((size_t)(hw0 + hw) << 6) + lane] = tile[lane][hw];
    }
}

// Kernel B: fused 5-variant OBMC warp.
// Pre-phase: one thread per (g,px) computes clamped tap offsets + validity-
// masked bilinear weights into LDS descriptors (no branches/redundant work in
// the hot loop). Gather phase: lanes-along-channels, 4 unconditional float4
// gathers per (g,i). Store phase: LDS bounce to pixel-major, coalesced
// nontemporal stores.
__global__ __launch_bounds__(256) void obmc_kernel(const float* __restrict__ xt,
                                                   const float* __restrict__ flow,
                                                   float* __restrict__ out) {
    __shared__ int4 dOff[5][64];    // clamped tap offsets (element idx, <<6)
    __shared__ float4 dW[5][64];    // validity-masked bilinear weights
    __shared__ float sm[64][65];    // [c][px] staging for coalesced stores

    const int bid = blockIdx.x;
    const int tx0 = (bid & 3) << 6;
    const int y = (bid >> 2) & 255;
    const int b = bid >> 10;
    const int t = threadIdx.x;
    const int wv = t >> 6;
    const int lane = t & 63;
    const int sp = lane >> 4;
    const int c4 = (lane & 15) << 2;

    const float* xtb = xt + ((size_t)b * HWHW << 6);
    const float* fb = flow + (size_t)b * 2 * HWHW;
    float* ob = out + (size_t)b * 5 * CC * HWHW + (size_t)y * WW + tx0;

    const int oys[5] = {0, 1, 0, -1, 0};
    const int oxs[5] = {0, 0, 1, 0, -1};

    // ---- pre-phase: 320 descriptors by 256 threads ----
    for (int idx = t; idx < 320; idx += 256) {
        const int g = idx >> 6, px = idx & 63;
        const int sy = y + oys[g];
        const int sx = tx0 + px + oxs[g];
        float fx = 0.f, fy = 0.f;
        if ((unsigned)sy < HH && (unsigned)sx < WW) {
            const int fo = sy * WW + sx;
            fx = fb[fo];
            fy = fb[HWHW + fo];
        }
        const float gx = (float)(tx0 + px) + fx;
        const float gy = (float)y + fy;
        const float x0f = floorf(gx);
        const float y0f = floorf(gy);
        const float fwx = gx - x0f;
        const float fwy = gy - y0f;
        const int ix0 = (int)x0f, iy0 = (int)y0f;
        const int ix1 = ix0 + 1, iy1 = iy0 + 1;
        const float vx0 = ((unsigned)ix0 < WW) ? 1.f : 0.f;
        const float vx1 = ((unsigned)ix1 < WW) ? 1.f : 0.f;
        const float vy0 = ((unsigned)iy0 < HH) ? 1.f : 0.f;
        const float vy1 = ((unsigned)iy1 < HH) ? 1.f : 0.f;
        const int xc0 = min(max(ix0, 0), WW - 1);
        const int xc1 = min(max(ix1, 0), WW - 1);
        const int yc0 = min(max(iy0, 0), HH - 1);
        const int yc1 = min(max(iy1, 0), HH - 1);
        dOff[g][px] = make_int4((yc0 * WW + xc0) << 6, (yc0 * WW + xc1) << 6,
                                (yc1 * WW + xc0) << 6, (yc1 * WW + xc1) << 6);
        dW[g][px] = make_float4((1.f - fwx) * (1.f - fwy) * vx0 * vy0,
                                fwx * (1.f - fwy) * vx1 * vy0,
                                (1.f - fwx) * fwy * vx0 * vy1,
                                fwx * fwy * vx1 * vy1);
    }
    __syncthreads();

    for (int g = 0; g < 5; ++g) {
        float4 acc[4];
#pragma unroll
        for (int i = 0; i < 4; ++i) {
            const int px = (wv << 4) + (i << 2) + sp;
            const int4 o = dOff[g][px];     // broadcast ds_read_b128
            const float4 w = dW[g][px];     // broadcast ds_read_b128
            const float4 v0 = *(const float4*)(xtb + o.x + c4);
            const float4 v1 = *(const float4*)(xtb + o.y + c4);
            const float4 v2 = *(const float4*)(xtb + o.z + c4);
            const float4 v3 = *(const float4*)(xtb + o.w + c4);
            float4 a;
            a.x = w.x * v0.x; a.y = w.x * v0.y; a.z = w.x * v0.z; a.w = w.x * v0.w;
            a.x = fmaf(w.y, v1.x, a.x); a.y = fmaf(w.y, v1.y, a.y);
            a.z = fmaf(w.y, v1.z, a.z); a.w = fmaf(w.y, v1.w, a.w);
            a.x = fmaf(w.z, v2.x, a.x); a.y = fmaf(w.z, v2.y, a.y);
            a.z = fmaf(w.z, v2.z, a.z); a.w = fmaf(w.z, v2.w, a.w);
            a.x = fmaf(w.w, v3.x, a.x); a.y = fmaf(w.w, v3.y, a.y);
            a.z = fmaf(w.w, v3.z, a.z); a.w = fmaf(w.w, v3.w, a.w);
            acc[i] = a;
        }
#pragma unroll
        for (int i = 0; i < 4; ++i) {
            const int px = (wv << 4) + (i << 2) + sp;
            sm[c4 + 0][px] = acc[i].x;
            sm[c4 + 1][px] = acc[i].y;
            sm[c4 + 2][px] = acc[i].z;
            sm[c4 + 3][px] = acc[i].w;
        }
        __syncthreads();
#pragma unroll
        for (int k = 0; k < 16; ++k) {
            const int c = (wv << 4) + k;
            __builtin_nontemporal_store(sm[c][lane],
                                        &ob[(size_t)(g * CC + c) * HWHW + lane]);
        }
        __syncthreads();
    }
}

extern "C" void kernel_launch(void* const* d_in, const int* in_sizes, int n_in,
                              void* d_out, int out_size, void* d_ws, size_t ws_size,
                              hipStream_t stream) {
    const float* x = (const float*)d_in[0];
    const float* flow = (const float*)d_in[1];
    float* out = (float*)d_out;
    float* xt = (float*)d_ws;  // 64 MiB scratch

    transpose_xk<<<dim3(HWHW / 64, BB), 256, 0, stream>>>(x, xt);
    obmc_kernel<<<BB * HH * (WW / 64), 256, 0, stream>>>(xt, flow, out);
}